// Round 1
// 287.599 us; speedup vs baseline: 1.0658x; 1.0658x over previous
//
#include <hip/hip_runtime.h>
#include <math.h>

#define NH 16
#define HDIM 64
#define D_ATTN 1024
#define KW 4
#define ATT_SCALE 0.125f
#define LKV_C 512
#define LQ_C 4096
#define B_C 4

typedef _Float16 f16;
typedef _Float16 f16x8 __attribute__((ext_vector_type(8)));
typedef _Float16 f16x4 __attribute__((ext_vector_type(4)));
typedef float f32x4 __attribute__((ext_vector_type(4)));

typedef __attribute__((address_space(3))) unsigned int as3_uint;
typedef __attribute__((address_space(1))) const unsigned int as1_uint;

__device__ __forceinline__ void gld_lds16(const f16* g, f16* l) {
    __builtin_amdgcn_global_load_lds((as1_uint*)g, (as3_uint*)l, 16, 0, 0);
}

// fp32 -> fp16
__global__ __launch_bounds__(256) void split_hi(const float* __restrict__ x,
                                                f16* __restrict__ hi, int n4) {
    int i = blockIdx.x * 256 + threadIdx.x;
    if (i >= n4) return;
    float4 v = ((const float4*)x)[i];
    ((f16x4*)hi)[i] = (f16x4){(f16)v.x, (f16)v.y, (f16)v.z, (f16)v.w};
}

// ---------------------------------------------------------------------------
// 128x128-tile GEMM (2-barrier structure) — kept for the kv projection
// (M=2048, N=2048: 256 blocks; the 256^2 kernel would only fill 64 CUs).
// ---------------------------------------------------------------------------
__global__ __launch_bounds__(256) void gemm_f16(const f16* __restrict__ A,
                                                const f16* __restrict__ B,
                                                float* __restrict__ C,
                                                int M, int N, int K) {
    __shared__ f16 smem[2 * 128 * 32];   // A | B, 16 KB
    f16* sA = smem;
    f16* sB = smem + 4096;

    const int t = threadIdx.x;
    const int w = t >> 6;
    const int lane = t & 63;
    const int bm = blockIdx.y * 128;
    const int bn = blockIdx.x * 128;
    const int wm = (w & 1) * 64;
    const int wn = (w >> 1) * 64;

    f32x4 acc[4][4] = {};

    const int frow = lane & 15;
    const int fchunk = lane >> 4;

    const int srow = t >> 2;
    const int chunk = (t & 3) ^ ((t >> 3) & 3);
    const size_t aoff0 = (size_t)(bm + srow) * K + chunk * 8;
    const size_t aoff1 = (size_t)(bm + 64 + srow) * K + chunk * 8;
    const size_t boff0 = (size_t)(bn + srow) * K + chunk * 8;
    const size_t boff1 = (size_t)(bn + 64 + srow) * K + chunk * 8;
    const unsigned loff0 = (w * 64) * 8;
    const unsigned loff1 = (256 + w * 64) * 8;

    gld_lds16(A + aoff0, sA + loff0);  gld_lds16(A + aoff1, sA + loff1);
    gld_lds16(B + boff0, sB + loff0);  gld_lds16(B + boff1, sB + loff1);

    for (int k0 = 0; k0 < K; k0 += 32) {
        __syncthreads();

        f16x8 a[4], b[4];
        #pragma unroll
        for (int i = 0; i < 4; ++i) {
            const int r = wm + i * 16 + frow;
            a[i] = *(const f16x8*)(sA + r * 32 + (fchunk ^ ((r >> 1) & 3)) * 8);
        }
        #pragma unroll
        for (int j = 0; j < 4; ++j) {
            const int r = wn + j * 16 + frow;
            b[j] = *(const f16x8*)(sB + r * 32 + (fchunk ^ ((r >> 1) & 3)) * 8);
        }

        __syncthreads();

        if (k0 + 32 < K) {
            const int kn = k0 + 32;
            gld_lds16(A + aoff0 + kn, sA + loff0);  gld_lds16(A + aoff1 + kn, sA + loff1);
            gld_lds16(B + boff0 + kn, sB + loff0);  gld_lds16(B + boff1 + kn, sB + loff1);
        }

        #pragma unroll
        for (int i = 0; i < 4; ++i)
            #pragma unroll
            for (int j = 0; j < 4; ++j)
                acc[i][j] = __builtin_amdgcn_mfma_f32_16x16x32_f16(a[i], b[j], acc[i][j], 0, 0, 0);
    }

    const int rbase = bm + wm + (lane >> 4) * 4;
    const int cbase = bn + wn + (lane & 15);
    #pragma unroll
    for (int i = 0; i < 4; ++i)
        #pragma unroll
        for (int j = 0; j < 4; ++j)
            #pragma unroll
            for (int r = 0; r < 4; ++r)
                C[(size_t)(rbase + i * 16 + r) * N + cbase + j * 16] = acc[i][j][r];
}

// ---------------------------------------------------------------------------
// 256x256-tile, 8-phase, counted-vmcnt GEMM (C = A[M,K] @ B[N,K]^T).
// 8 waves (2M x 4N, interleaved row mapping: wave-m stride 16 inside 32-row
// groups so each quadrant consumes exactly one 128-row half-tile).
// LDS 128 KiB: A0|A1|B0|B1, each [256][64] f16, rows XOR-chunk-swizzled
// (q ^= r&7) via pre-swizzled global source (linear global_load_lds dest).
// vmcnt(6) at phases 4/8 only (3 half-tiles in flight); vmcnt(0) peel on the
// last iteration. Requires M%256==0, N%256==0, K%128==0, grid%8==0.
// ---------------------------------------------------------------------------
__device__ __forceinline__ void stage_half(const f16* __restrict__ g, size_t row0,
                                           int K, int kcol, f16* l) {
    const int t = threadIdx.x;
    #pragma unroll
    for (int i = 0; i < 2; ++i) {
        const int idx = i * 512 + t;                 // 1024 x 16B = 128 rows
        const int r = idx >> 3;
        const int qg = (idx & 7) ^ (r & 7);          // inverse (= same) swizzle
        gld_lds16(g + (row0 + r) * (size_t)K + kcol + qg * 8, l + idx * 8);
    }
}

#define BAR __builtin_amdgcn_s_barrier()
#define VM6 asm volatile("s_waitcnt vmcnt(6)" ::: "memory")
#define VM8 asm volatile("s_waitcnt vmcnt(8)" ::: "memory")
#define VM0 asm volatile("s_waitcnt vmcnt(0)" ::: "memory")

#define RD_A(S, mh)                                                         \
    { _Pragma("unroll") for (int mi = 0; mi < 4; ++mi) {                    \
        const f16* p = (S) + ((mh) * 128 + mi * 32 + arow) * 64;            \
        a[0][mi] = *(const f16x8*)(p + q0);                                 \
        a[1][mi] = *(const f16x8*)(p + q1); } }

#define RD_B(S, nh)                                                         \
    { _Pragma("unroll") for (int ni = 0; ni < 2; ++ni) {                    \
        const f16* p = (S) + (((nh) * 2 + ni) * 64 + brow) * 64;            \
        b[0][(nh) * 2 + ni] = *(const f16x8*)(p + q0);                      \
        b[1][(nh) * 2 + ni] = *(const f16x8*)(p + q1); } }

#define QUAD(mh, nh)                                                        \
    { __builtin_amdgcn_s_setprio(1);                                        \
      _Pragma("unroll") for (int mi = 0; mi < 4; ++mi)                      \
      _Pragma("unroll") for (int ni = 0; ni < 2; ++ni) {                    \
          f32x4& c = acc[(mh) * 4 + mi][(nh) * 2 + ni];                     \
          c = __builtin_amdgcn_mfma_f32_16x16x32_f16(a[0][mi], b[0][(nh) * 2 + ni], c, 0, 0, 0); \
          c = __builtin_amdgcn_mfma_f32_16x16x32_f16(a[1][mi], b[1][(nh) * 2 + ni], c, 0, 0, 0); \
      }                                                                     \
      __builtin_amdgcn_s_setprio(0); }

__global__ __launch_bounds__(512, 2) void gemm256(const f16* __restrict__ A,
                                                  const f16* __restrict__ B,
                                                  float* __restrict__ C,
                                                  int M, int N, int K) {
    __shared__ __align__(16) f16 smem[4 * 16384];   // 128 KiB
    f16* const sA0 = smem;
    f16* const sA1 = smem + 16384;
    f16* const sB0 = smem + 32768;
    f16* const sB1 = smem + 49152;

    const int t = threadIdx.x;
    const int lane = t & 63;
    const int w = t >> 6;
    const int wr = w >> 2;                // 0..1 (M)
    const int wc = w & 3;                 // 0..3 (N)
    const int frow = lane & 15;
    const int fc = lane >> 4;

    // XCD-aware bijective swizzle (grid size is a multiple of 8)
    const int nbx = N >> 8;
    const int nwg = gridDim.x;
    const int wg = (blockIdx.x & 7) * (nwg >> 3) + (blockIdx.x >> 3);
    const int bm = (wg / nbx) << 8;
    const int bn = (wg % nbx) << 8;

    const int arow = wr * 16 + frow;      // + m*32  (interleaved wave rows)
    const int brow = wc * 16 + frow;      // + n*64
    const int q0 = (fc ^ (frow & 7)) * 8;        // swizzled chunk, kstep 0
    const int q1 = ((4 + fc) ^ (frow & 7)) * 8;  // swizzled chunk, kstep 1

    f32x4 acc[8][4] = {};
    f16x8 a[2][4], b[2][4];

    // prologue: stage K-tiles 0 (buf0) and 1 (buf1), t0-first issue order
    stage_half(A, bm,       K, 0,  sA0);
    stage_half(B, bn,       K, 0,  sB0);
    stage_half(B, bn + 128, K, 0,  sB0 + 8192);
    stage_half(A, bm + 128, K, 0,  sA0 + 8192);
    stage_half(A, bm,       K, 64, sA1);
    stage_half(B, bn,       K, 64, sB1);
    stage_half(B, bn + 128, K, 64, sB1 + 8192);
    stage_half(A, bm + 128, K, 64, sA1 + 8192);
    VM8;                                   // K-tile 0 landed (tile 1 in flight)
    BAR;

    const int NT = K >> 7;                 // 2 K-tiles (of 64) per iteration
    for (int it = 0; it < NT; ++it) {
        const bool lastit = (it == NT - 1);
        const int kc2 = (it * 2 + 2) << 6;
        const int kc3 = (it * 2 + 3) << 6;

        // ph1: consume A-h0 + B-h0 of buf0
        RD_A(sA0, 0); RD_B(sB0, 0);
        BAR; QUAD(0, 0); BAR;
        // ph2: consume B-h1; restage A-h0/B-h0 (dead since ph1)
        RD_B(sB0, 1);
        if (!lastit) { stage_half(A, bm, K, kc2, sA0); stage_half(B, bn, K, kc2, sB0); }
        BAR; QUAD(0, 1); BAR;
        // ph3: consume A-h1; restage B-h1 (dead since ph2)
        RD_A(sA0, 1);
        if (!lastit) stage_half(B, bn + 128, K, kc2, sB0 + 8192);
        BAR; QUAD(1, 0); BAR;
        // ph4: counted wait -> K-tile (2it+1) fully landed; restage A-h1
        if (lastit) { VM0; } else { VM6; stage_half(A, bm + 128, K, kc2, sA0 + 8192); }
        BAR; QUAD(1, 1); BAR;

        // ph5: consume A-h0 + B-h0 of buf1
        RD_A(sA1, 0); RD_B(sB1, 0);
        BAR; QUAD(0, 0); BAR;
        // ph6
        RD_B(sB1, 1);
        if (!lastit) { stage_half(A, bm, K, kc3, sA1); stage_half(B, bn, K, kc3, sB1); }
        BAR; QUAD(0, 1); BAR;
        // ph7
        RD_A(sA1, 1);
        if (!lastit) stage_half(B, bn + 128, K, kc3, sB1 + 8192);
        BAR; QUAD(1, 0); BAR;
        // ph8: counted wait -> K-tile (2it+2) fully landed; restage A-h1
        if (!lastit) { VM6; stage_half(A, bm + 128, K, kc3, sA1 + 8192); }
        BAR; QUAD(1, 1); BAR;
    }

    // epilogue: C/D layout col = lane&15, row = (lane>>4)*4 + reg
    const size_t rb = (size_t)bm + wr * 16 + ((lane >> 4) << 2);
    const int cb = bn + wc * 16 + (lane & 15);
    #pragma unroll
    for (int m = 0; m < 8; ++m)
        #pragma unroll
        for (int n = 0; n < 4; ++n)
            #pragma unroll
            for (int rr = 0; rr < 4; ++rr)
                C[(rb + m * 32 + rr) * N + cb + n * 64] = acc[m][n][rr];
}

// One wave = one query row x 4 heads. lane = 16*hh + s; lane owns d in [4s, 4s+4).
__global__ __launch_bounds__(256) void attn_kernel(const float* __restrict__ qh,   // (B*LQ, 1024) fp32
                                                   const float* __restrict__ kvp,  // (B*LKV, 2048): K|V fp32
                                                   const int* __restrict__ seg_id, // (B*LQ)
                                                   f16* __restrict__ attn_o) {     // (B*LQ, 1024) fp16
    const int wid = blockIdx.x * 4 + (threadIdx.x >> 6);
    const int lane = threadIdx.x & 63;
    const int row = wid >> 2;          // b*LQ + qi
    const int hg  = wid & 3;
    const int hh = lane >> 4;
    const int s  = lane & 15;
    const int head = hg * 4 + hh;
    const int b = row >> 12;           // LQ = 4096
    const int seg = seg_id[row];
    const int dbase = head * HDIM + 4 * s;

    const float4 q4 = *(const float4*)(qh + (size_t)row * D_ATTN + dbase);
    const float* kvb = kvp + (size_t)b * LKV_C * (2 * D_ATTN);

    float sc[KW];
    #pragma unroll
    for (int w = 0; w < KW; ++w) {
        const int j = seg - w;
        float p = 0.f;
        if (j >= 0) {
            const float4 k4 = *(const float4*)(kvb + (size_t)j * (2 * D_ATTN) + dbase);
            p = q4.x * k4.x + q4.y * k4.y + q4.z * k4.z + q4.w * k4.w;
        }
        p += __shfl_xor(p, 1);
        p += __shfl_xor(p, 2);
        p += __shfl_xor(p, 4);
        p += __shfl_xor(p, 8);
        sc[w] = (j >= 0) ? p * ATT_SCALE : -1e30f;
    }

    const float m = fmaxf(fmaxf(sc[0], sc[1]), fmaxf(sc[2], sc[3]));
    float e[KW], sum = 0.f;
    #pragma unroll
    for (int w = 0; w < KW; ++w) {
        e[w] = __expf(sc[w] - m);
        sum += e[w];
    }
    const float inv = 1.f / sum;

    float4 o = make_float4(0.f, 0.f, 0.f, 0.f);
    #pragma unroll
    for (int w = 0; w < KW; ++w) {
        const int j = seg - w;
        if (j >= 0) {
            const float4 v4 = *(const float4*)(kvb + (size_t)j * (2 * D_ATTN) + D_ATTN + dbase);
            const float c = e[w] * inv;
            o.x = fmaf(c, v4.x, o.x);
            o.y = fmaf(c, v4.y, o.y);
            o.z = fmaf(c, v4.z, o.z);
            o.w = fmaf(c, v4.w, o.w);
        }
    }

    *(f16x4*)(attn_o + (size_t)row * D_ATTN + dbase) =
        (f16x4){(f16)o.x, (f16)o.y, (f16)o.z, (f16)o.w};
}

extern "C" void kernel_launch(void* const* d_in, const int* in_sizes, int n_in,
                              void* d_out, int out_size, void* d_ws, size_t ws_size,
                              hipStream_t stream) {
    const float* q      = (const float*)d_in[0]; // (4,4096,1024)
    const float* kv_src = (const float*)d_in[1]; // (4,512,1024)
    const int*   seg    = (const int*)  d_in[2]; // (4,4096)
    const float* Wq     = (const float*)d_in[3]; // (1024,1024)
    const float* Wkv    = (const float*)d_in[4]; // (2048,1024)
    const float* Wo     = (const float*)d_in[5]; // (1024,1024)
    float* out = (float*)d_out;

    const int M  = B_C * LQ_C;    // 16384
    const int Mk = B_C * LKV_C;   // 2048

    // workspace layout (~60 MB)
    f16* q_hi   = (f16*)d_ws;                       // 32 MB
    f16* kvs_hi = q_hi   + (size_t)M * D_ATTN;      // 4 MB
    f16* Wq_hi  = kvs_hi + (size_t)Mk * 1024;       // 2 MB
    f16* Wkv_hi = Wq_hi  + 1024 * 1024;             // 4 MB
    f16* Wo_hi  = Wkv_hi + 2048 * 1024;             // 2 MB
    float* kvp  = (float*)(Wo_hi + 1024 * 1024);    // 16 MB
    f16* attn_o = q_hi;             // alias: q_hi dead after GEMM1
    float* qh = (float*)d_out;      // qh parked in d_out, overwritten by GEMM3

    // 1. fp32 -> fp16 conversions
    split_hi<<<(M * D_ATTN) / 1024, 256, 0, stream>>>(q, q_hi, (M * D_ATTN) / 4);
    split_hi<<<(Mk * 1024) / 1024, 256, 0, stream>>>(kv_src, kvs_hi, (Mk * 1024) / 4);
    split_hi<<<(1024 * 1024) / 1024, 256, 0, stream>>>(Wq, Wq_hi, (1024 * 1024) / 4);
    split_hi<<<(2048 * 1024) / 1024, 256, 0, stream>>>(Wkv, Wkv_hi, (2048 * 1024) / 4);
    split_hi<<<(1024 * 1024) / 1024, 256, 0, stream>>>(Wo, Wo_hi, (1024 * 1024) / 4);

    // 2. qh = q @ Wq^T  (into d_out) — 256^2 8-phase kernel, 256 blocks
    gemm256<<<(M / 256) * (1024 / 256), 512, 0, stream>>>(q_hi, Wq_hi, qh, M, 1024, 1024);
    // 3. kvp = kv_src @ Wkv^T — 128^2 kernel (better CU coverage at M=2048)
    gemm_f16<<<dim3(2048 / 128, Mk / 128), 256, 0, stream>>>(kvs_hi, Wkv_hi, kvp, Mk, 2048, 1024);
    // 4. windowed attention -> fp16 attn (aliases q_hi)
    attn_kernel<<<(M * NH) / 16, 256, 0, stream>>>(qh, kvp, seg, attn_o);
    // 5. out = attn @ Wo^T  (overwrites d_out)
    gemm256<<<(M / 256) * (1024 / 256), 512, 0, stream>>>(attn_o, Wo_hi, out, M, 1024, 1024);
}

// Round 2
// 271.774 us; speedup vs baseline: 1.1279x; 1.0582x over previous
//
#include <hip/hip_runtime.h>
#include <math.h>

#define NH 16
#define HDIM 64
#define D_ATTN 1024
#define KW 4
#define ATT_SCALE 0.125f
#define LKV_C 512
#define LQ_C 4096
#define B_C 4

typedef _Float16 f16;
typedef _Float16 f16x8 __attribute__((ext_vector_type(8)));
typedef _Float16 f16x4 __attribute__((ext_vector_type(4)));
typedef float f32x4 __attribute__((ext_vector_type(4)));

typedef __attribute__((address_space(3))) unsigned int as3_uint;
typedef __attribute__((address_space(1))) const unsigned int as1_uint;

__device__ __forceinline__ void gld_lds16(const f16* g, f16* l) {
    __builtin_amdgcn_global_load_lds((as1_uint*)g, (as3_uint*)l, 16, 0, 0);
}

// fp32 -> fp16
__global__ __launch_bounds__(256) void split_hi(const float* __restrict__ x,
                                                f16* __restrict__ hi, int n4) {
    int i = blockIdx.x * 256 + threadIdx.x;
    if (i >= n4) return;
    float4 v = ((const float4*)x)[i];
    ((f16x4*)hi)[i] = (f16x4){(f16)v.x, (f16)v.y, (f16)v.z, (f16)v.w};
}

// ---------------------------------------------------------------------------
// 128x128-tile GEMM (2-barrier structure) — kept for the kv projection
// (M=2048, N=2048: 256 blocks). Templated output type (fp32 or fp16).
// ---------------------------------------------------------------------------
template <typename OT>
__global__ __launch_bounds__(256) void gemm_f16(const f16* __restrict__ A,
                                                const f16* __restrict__ B,
                                                OT* __restrict__ C,
                                                int M, int N, int K) {
    __shared__ f16 smem[2 * 128 * 32];   // A | B, 16 KB
    f16* sA = smem;
    f16* sB = smem + 4096;

    const int t = threadIdx.x;
    const int w = t >> 6;
    const int lane = t & 63;
    const int bm = blockIdx.y * 128;
    const int bn = blockIdx.x * 128;
    const int wm = (w & 1) * 64;
    const int wn = (w >> 1) * 64;

    f32x4 acc[4][4] = {};

    const int frow = lane & 15;
    const int fchunk = lane >> 4;

    const int srow = t >> 2;
    const int chunk = (t & 3) ^ ((t >> 3) & 3);
    const size_t aoff0 = (size_t)(bm + srow) * K + chunk * 8;
    const size_t aoff1 = (size_t)(bm + 64 + srow) * K + chunk * 8;
    const size_t boff0 = (size_t)(bn + srow) * K + chunk * 8;
    const size_t boff1 = (size_t)(bn + 64 + srow) * K + chunk * 8;
    const unsigned loff0 = (w * 64) * 8;
    const unsigned loff1 = (256 + w * 64) * 8;

    gld_lds16(A + aoff0, sA + loff0);  gld_lds16(A + aoff1, sA + loff1);
    gld_lds16(B + boff0, sB + loff0);  gld_lds16(B + boff1, sB + loff1);

    for (int k0 = 0; k0 < K; k0 += 32) {
        __syncthreads();

        f16x8 a[4], b[4];
        #pragma unroll
        for (int i = 0; i < 4; ++i) {
            const int r = wm + i * 16 + frow;
            a[i] = *(const f16x8*)(sA + r * 32 + (fchunk ^ ((r >> 1) & 3)) * 8);
        }
        #pragma unroll
        for (int j = 0; j < 4; ++j) {
            const int r = wn + j * 16 + frow;
            b[j] = *(const f16x8*)(sB + r * 32 + (fchunk ^ ((r >> 1) & 3)) * 8);
        }

        __syncthreads();

        if (k0 + 32 < K) {
            const int kn = k0 + 32;
            gld_lds16(A + aoff0 + kn, sA + loff0);  gld_lds16(A + aoff1 + kn, sA + loff1);
            gld_lds16(B + boff0 + kn, sB + loff0);  gld_lds16(B + boff1 + kn, sB + loff1);
        }

        #pragma unroll
        for (int i = 0; i < 4; ++i)
            #pragma unroll
            for (int j = 0; j < 4; ++j)
                acc[i][j] = __builtin_amdgcn_mfma_f32_16x16x32_f16(a[i], b[j], acc[i][j], 0, 0, 0);
    }

    const int rbase = bm + wm + (lane >> 4) * 4;
    const int cbase = bn + wn + (lane & 15);
    #pragma unroll
    for (int i = 0; i < 4; ++i)
        #pragma unroll
        for (int j = 0; j < 4; ++j)
            #pragma unroll
            for (int r = 0; r < 4; ++r)
                C[(size_t)(rbase + i * 16 + r) * N + cbase + j * 16] = (OT)acc[i][j][r];
}

// ---------------------------------------------------------------------------
// 256x256-tile, 8-phase, counted-vmcnt GEMM (C = A[M,K] @ B[N,K]^T).
// Templated output type. See round-0 comments for schedule details.
// ---------------------------------------------------------------------------
__device__ __forceinline__ void stage_half(const f16* __restrict__ g, size_t row0,
                                           int K, int kcol, f16* l) {
    const int t = threadIdx.x;
    #pragma unroll
    for (int i = 0; i < 2; ++i) {
        const int idx = i * 512 + t;                 // 1024 x 16B = 128 rows
        const int r = idx >> 3;
        const int qg = (idx & 7) ^ (r & 7);          // inverse (= same) swizzle
        gld_lds16(g + (row0 + r) * (size_t)K + kcol + qg * 8, l + idx * 8);
    }
}

#define BAR __builtin_amdgcn_s_barrier()
#define VM6 asm volatile("s_waitcnt vmcnt(6)" ::: "memory")
#define VM8 asm volatile("s_waitcnt vmcnt(8)" ::: "memory")
#define VM0 asm volatile("s_waitcnt vmcnt(0)" ::: "memory")

#define RD_A(S, mh)                                                         \
    { _Pragma("unroll") for (int mi = 0; mi < 4; ++mi) {                    \
        const f16* p = (S) + ((mh) * 128 + mi * 32 + arow) * 64;            \
        a[0][mi] = *(const f16x8*)(p + q0);                                 \
        a[1][mi] = *(const f16x8*)(p + q1); } }

#define RD_B(S, nh)                                                         \
    { _Pragma("unroll") for (int ni = 0; ni < 2; ++ni) {                    \
        const f16* p = (S) + (((nh) * 2 + ni) * 64 + brow) * 64;            \
        b[0][(nh) * 2 + ni] = *(const f16x8*)(p + q0);                      \
        b[1][(nh) * 2 + ni] = *(const f16x8*)(p + q1); } }

#define QUAD(mh, nh)                                                        \
    { __builtin_amdgcn_s_setprio(1);                                        \
      _Pragma("unroll") for (int mi = 0; mi < 4; ++mi)                      \
      _Pragma("unroll") for (int ni = 0; ni < 2; ++ni) {                    \
          f32x4& c = acc[(mh) * 4 + mi][(nh) * 2 + ni];                     \
          c = __builtin_amdgcn_mfma_f32_16x16x32_f16(a[0][mi], b[0][(nh) * 2 + ni], c, 0, 0, 0); \
          c = __builtin_amdgcn_mfma_f32_16x16x32_f16(a[1][mi], b[1][(nh) * 2 + ni], c, 0, 0, 0); \
      }                                                                     \
      __builtin_amdgcn_s_setprio(0); }

template <typename OT>
__global__ __launch_bounds__(512, 2) void gemm256(const f16* __restrict__ A,
                                                  const f16* __restrict__ B,
                                                  OT* __restrict__ C,
                                                  int M, int N, int K) {
    __shared__ __align__(16) f16 smem[4 * 16384];   // 128 KiB
    f16* const sA0 = smem;
    f16* const sA1 = smem + 16384;
    f16* const sB0 = smem + 32768;
    f16* const sB1 = smem + 49152;

    const int t = threadIdx.x;
    const int lane = t & 63;
    const int w = t >> 6;
    const int wr = w >> 2;                // 0..1 (M)
    const int wc = w & 3;                 // 0..3 (N)
    const int frow = lane & 15;
    const int fc = lane >> 4;

    // XCD-aware bijective swizzle (grid size is a multiple of 8)
    const int nbx = N >> 8;
    const int nwg = gridDim.x;
    const int wg = (blockIdx.x & 7) * (nwg >> 3) + (blockIdx.x >> 3);
    const int bm = (wg / nbx) << 8;
    const int bn = (wg % nbx) << 8;

    const int arow = wr * 16 + frow;      // + m*32  (interleaved wave rows)
    const int brow = wc * 16 + frow;      // + n*64
    const int q0 = (fc ^ (frow & 7)) * 8;        // swizzled chunk, kstep 0
    const int q1 = ((4 + fc) ^ (frow & 7)) * 8;  // swizzled chunk, kstep 1

    f32x4 acc[8][4] = {};
    f16x8 a[2][4], b[2][4];

    // prologue: stage K-tiles 0 (buf0) and 1 (buf1)
    stage_half(A, bm,       K, 0,  sA0);
    stage_half(B, bn,       K, 0,  sB0);
    stage_half(B, bn + 128, K, 0,  sB0 + 8192);
    stage_half(A, bm + 128, K, 0,  sA0 + 8192);
    stage_half(A, bm,       K, 64, sA1);
    stage_half(B, bn,       K, 64, sB1);
    stage_half(B, bn + 128, K, 64, sB1 + 8192);
    stage_half(A, bm + 128, K, 64, sA1 + 8192);
    VM8;                                   // K-tile 0 landed (tile 1 in flight)
    BAR;

    const int NT = K >> 7;                 // 2 K-tiles (of 64) per iteration
    for (int it = 0; it < NT; ++it) {
        const bool lastit = (it == NT - 1);
        const int kc2 = (it * 2 + 2) << 6;
        const int kc3 = (it * 2 + 3) << 6;

        // ph1: consume A-h0 + B-h0 of buf0
        RD_A(sA0, 0); RD_B(sB0, 0);
        BAR; QUAD(0, 0); BAR;
        // ph2
        RD_B(sB0, 1);
        if (!lastit) { stage_half(A, bm, K, kc2, sA0); stage_half(B, bn, K, kc2, sB0); }
        BAR; QUAD(0, 1); BAR;
        // ph3
        RD_A(sA0, 1);
        if (!lastit) stage_half(B, bn + 128, K, kc2, sB0 + 8192);
        BAR; QUAD(1, 0); BAR;
        // ph4
        if (lastit) { VM0; } else { VM6; stage_half(A, bm + 128, K, kc2, sA0 + 8192); }
        BAR; QUAD(1, 1); BAR;

        // ph5: consume A-h0 + B-h0 of buf1
        RD_A(sA1, 0); RD_B(sB1, 0);
        BAR; QUAD(0, 0); BAR;
        // ph6
        RD_B(sB1, 1);
        if (!lastit) { stage_half(A, bm, K, kc3, sA1); stage_half(B, bn, K, kc3, sB1); }
        BAR; QUAD(0, 1); BAR;
        // ph7
        RD_A(sA1, 1);
        if (!lastit) stage_half(B, bn + 128, K, kc3, sB1 + 8192);
        BAR; QUAD(1, 0); BAR;
        // ph8
        if (!lastit) { VM6; stage_half(A, bm + 128, K, kc3, sA1 + 8192); }
        BAR; QUAD(1, 1); BAR;
    }

    // epilogue: C/D layout col = lane&15, row = (lane>>4)*4 + reg
    const size_t rb = (size_t)bm + wr * 16 + ((lane >> 4) << 2);
    const int cb = bn + wc * 16 + (lane & 15);
    #pragma unroll
    for (int m = 0; m < 8; ++m)
        #pragma unroll
        for (int n = 0; n < 4; ++n)
            #pragma unroll
            for (int rr = 0; rr < 4; ++rr)
                C[(rb + m * 32 + rr) * N + cb + n * 64] = (OT)acc[m][n][rr];
}

// ---------------------------------------------------------------------------
// Windowed attention, all-fp16 I/O, 4 rows per wave (ILP over 4 independent
// latency chains). Block = 4 waves = 4 head-groups; block b handles rows
// 4b..4b+3. lane = 16*hh + s; lane owns dims [4s, 4s+4) of head hg*4+hh.
// ---------------------------------------------------------------------------
__global__ __launch_bounds__(256) void attn_kernel(const f16* __restrict__ qh,   // (B*LQ, 1024) fp16
                                                   const f16* __restrict__ kvp,  // (B*LKV, 2048): K|V fp16
                                                   const int* __restrict__ seg_id, // (B*LQ)
                                                   f16* __restrict__ attn_o) {     // (B*LQ, 1024) fp16
    const int hg = threadIdx.x >> 6;
    const int lane = threadIdx.x & 63;
    const int r0 = blockIdx.x << 2;      // 4 consecutive rows (same batch: LQ=4096)
    const int hh = lane >> 4;
    const int s  = lane & 15;
    const int dbase = (hg * 4 + hh) * HDIM + 4 * s;
    const int b = r0 >> 12;
    const f16* kvb = kvp + (size_t)b * LKV_C * (2 * D_ATTN);

    int seg[4];
    float4 q[4];
    #pragma unroll
    for (int i = 0; i < 4; ++i) {
        seg[i] = seg_id[r0 + i];
        f16x4 qv = *(const f16x4*)(qh + (size_t)(r0 + i) * D_ATTN + dbase);
        q[i] = make_float4((float)qv.x, (float)qv.y, (float)qv.z, (float)qv.w);
    }

    // partial dots: 16 independent gathers, then 16 independent butterflies
    float sc[4][KW];
    #pragma unroll
    for (int i = 0; i < 4; ++i)
        #pragma unroll
        for (int w = 0; w < KW; ++w) {
            const int j = seg[i] - w;
            float p = 0.f;
            if (j >= 0) {
                f16x4 k4 = *(const f16x4*)(kvb + (size_t)j * (2 * D_ATTN) + dbase);
                p = q[i].x * (float)k4.x + q[i].y * (float)k4.y +
                    q[i].z * (float)k4.z + q[i].w * (float)k4.w;
            }
            sc[i][w] = p;
        }
    #pragma unroll
    for (int i = 0; i < 4; ++i)
        #pragma unroll
        for (int w = 0; w < KW; ++w) {
            float p = sc[i][w];
            p += __shfl_xor(p, 1);
            p += __shfl_xor(p, 2);
            p += __shfl_xor(p, 4);
            p += __shfl_xor(p, 8);
            sc[i][w] = (seg[i] - w >= 0) ? p * ATT_SCALE : -1e30f;
        }

    // softmax + V gather per row
    #pragma unroll
    for (int i = 0; i < 4; ++i) {
        const float m = fmaxf(fmaxf(sc[i][0], sc[i][1]), fmaxf(sc[i][2], sc[i][3]));
        float e[KW], sum = 0.f;
        #pragma unroll
        for (int w = 0; w < KW; ++w) {
            e[w] = __expf(sc[i][w] - m);
            sum += e[w];
        }
        const float inv = 1.f / sum;

        float4 o = make_float4(0.f, 0.f, 0.f, 0.f);
        #pragma unroll
        for (int w = 0; w < KW; ++w) {
            const int j = seg[i] - w;
            if (j >= 0) {
                f16x4 v4 = *(const f16x4*)(kvb + (size_t)j * (2 * D_ATTN) + D_ATTN + dbase);
                const float c = e[w] * inv;
                o.x = fmaf(c, (float)v4.x, o.x);
                o.y = fmaf(c, (float)v4.y, o.y);
                o.z = fmaf(c, (float)v4.z, o.z);
                o.w = fmaf(c, (float)v4.w, o.w);
            }
        }
        *(f16x4*)(attn_o + (size_t)(r0 + i) * D_ATTN + dbase) =
            (f16x4){(f16)o.x, (f16)o.y, (f16)o.z, (f16)o.w};
    }
}

extern "C" void kernel_launch(void* const* d_in, const int* in_sizes, int n_in,
                              void* d_out, int out_size, void* d_ws, size_t ws_size,
                              hipStream_t stream) {
    const float* q      = (const float*)d_in[0]; // (4,4096,1024)
    const float* kv_src = (const float*)d_in[1]; // (4,512,1024)
    const int*   seg    = (const int*)  d_in[2]; // (4,4096)
    const float* Wq     = (const float*)d_in[3]; // (1024,1024)
    const float* Wkv    = (const float*)d_in[4]; // (2048,1024)
    const float* Wo     = (const float*)d_in[5]; // (1024,1024)
    float* out = (float*)d_out;

    const int M  = B_C * LQ_C;    // 16384
    const int Mk = B_C * LKV_C;   // 2048

    // workspace layout (~52 MB)
    f16* q_hi   = (f16*)d_ws;                       // 32 MB
    f16* kvs_hi = q_hi   + (size_t)M * D_ATTN;      // 4 MB
    f16* Wq_hi  = kvs_hi + (size_t)Mk * 1024;       // 2 MB
    f16* Wkv_hi = Wq_hi  + 1024 * 1024;             // 4 MB
    f16* Wo_hi  = Wkv_hi + 2048 * 1024;             // 2 MB
    f16* kvp    = Wo_hi  + 1024 * 1024;             // 8 MB (fp16 K|V)
    f16* attn_o = q_hi;             // alias: q_hi dead after GEMM1
    f16* qh16   = (f16*)d_out;      // qh (fp16) parked in d_out, overwritten by GEMM4

    // 1. fp32 -> fp16 conversions
    split_hi<<<(M * D_ATTN) / 1024, 256, 0, stream>>>(q, q_hi, (M * D_ATTN) / 4);
    split_hi<<<(Mk * 1024) / 1024, 256, 0, stream>>>(kv_src, kvs_hi, (Mk * 1024) / 4);
    split_hi<<<(1024 * 1024) / 1024, 256, 0, stream>>>(Wq, Wq_hi, (1024 * 1024) / 4);
    split_hi<<<(2048 * 1024) / 1024, 256, 0, stream>>>(Wkv, Wkv_hi, (2048 * 1024) / 4);
    split_hi<<<(1024 * 1024) / 1024, 256, 0, stream>>>(Wo, Wo_hi, (1024 * 1024) / 4);

    // 2. qh16 = q @ Wq^T  (fp16, into d_out)
    gemm256<f16><<<(M / 256) * (1024 / 256), 512, 0, stream>>>(q_hi, Wq_hi, qh16, M, 1024, 1024);
    // 3. kvp = kv_src @ Wkv^T  (fp16)
    gemm_f16<f16><<<dim3(2048 / 128, Mk / 128), 256, 0, stream>>>(kvs_hi, Wkv_hi, kvp, Mk, 2048, 1024);
    // 4. windowed attention -> fp16 attn (aliases q_hi)
    attn_kernel<<<M / 4, 256, 0, stream>>>(qh16, kvp, seg, attn_o);
    // 5. out = attn @ Wo^T  (fp32, overwrites d_out)
    gemm256<float><<<(M / 256) * (1024 / 256), 512, 0, stream>>>(attn_o, Wo_hi, out, M, 1024, 1024);
}

// Round 3
// 266.480 us; speedup vs baseline: 1.1503x; 1.0199x over previous
//
#include <hip/hip_runtime.h>
#include <math.h>

#define NH 16
#define HDIM 64
#define D_ATTN 1024
#define KW 4
#define ATT_SCALE 0.125f
#define LKV_C 512
#define LQ_C 4096
#define B_C 4

typedef _Float16 f16;
typedef _Float16 f16x8 __attribute__((ext_vector_type(8)));
typedef _Float16 f16x4 __attribute__((ext_vector_type(4)));
typedef float f32x4 __attribute__((ext_vector_type(4)));

typedef __attribute__((address_space(3))) unsigned int as3_uint;
typedef __attribute__((address_space(1))) const unsigned int as1_uint;

__device__ __forceinline__ void gld_lds16(const f16* g, f16* l) {
    __builtin_amdgcn_global_load_lds((as1_uint*)g, (as3_uint*)l, 16, 0, 0);
}

// ---------------------------------------------------------------------------
// One-shot fp32 -> fp16 conversion of all five inputs (segment table in
// float4 units; grid covers exactly 5,767,168 float4s = 22528 blocks x 256).
// ---------------------------------------------------------------------------
#define SEG_Q   4194304          // 4*4096*1024/4
#define SEG_KV  (SEG_Q + 524288) // + 4*512*1024/4
#define SEG_WQ  (SEG_KV + 262144)
#define SEG_WKV (SEG_WQ + 524288)
#define SEG_END (SEG_WKV + 262144)

__global__ __launch_bounds__(256) void split_all(const float* __restrict__ q,
                                                 const float* __restrict__ kv,
                                                 const float* __restrict__ Wq,
                                                 const float* __restrict__ Wkv,
                                                 const float* __restrict__ Wo,
                                                 f16* __restrict__ q_hi,
                                                 f16* __restrict__ kvs_hi,
                                                 f16* __restrict__ Wq_hi,
                                                 f16* __restrict__ Wkv_hi,
                                                 f16* __restrict__ Wo_hi) {
    const int i = blockIdx.x * 256 + threadIdx.x;
    const float* src; f16* dst; int base;
    if (i < SEG_Q)        { src = q;   dst = q_hi;   base = 0; }
    else if (i < SEG_KV)  { src = kv;  dst = kvs_hi; base = SEG_Q; }
    else if (i < SEG_WQ)  { src = Wq;  dst = Wq_hi;  base = SEG_KV; }
    else if (i < SEG_WKV) { src = Wkv; dst = Wkv_hi; base = SEG_WQ; }
    else                  { src = Wo;  dst = Wo_hi;  base = SEG_WKV; }
    const int j = i - base;
    float4 v = ((const float4*)src)[j];
    ((f16x4*)dst)[j] = (f16x4){(f16)v.x, (f16)v.y, (f16)v.z, (f16)v.w};
}

// ---------------------------------------------------------------------------
// 128x128-tile GEMM (2-barrier structure) — kept for the kv projection
// (M=2048, N=2048: 256 blocks). Templated output type (fp32 or fp16).
// ---------------------------------------------------------------------------
template <typename OT>
__global__ __launch_bounds__(256) void gemm_f16(const f16* __restrict__ A,
                                                const f16* __restrict__ B,
                                                OT* __restrict__ C,
                                                int M, int N, int K) {
    __shared__ f16 smem[2 * 128 * 32];   // A | B, 16 KB
    f16* sA = smem;
    f16* sB = smem + 4096;

    const int t = threadIdx.x;
    const int w = t >> 6;
    const int lane = t & 63;
    const int bm = blockIdx.y * 128;
    const int bn = blockIdx.x * 128;
    const int wm = (w & 1) * 64;
    const int wn = (w >> 1) * 64;

    f32x4 acc[4][4] = {};

    const int frow = lane & 15;
    const int fchunk = lane >> 4;

    const int srow = t >> 2;
    const int chunk = (t & 3) ^ ((t >> 3) & 3);
    const size_t aoff0 = (size_t)(bm + srow) * K + chunk * 8;
    const size_t aoff1 = (size_t)(bm + 64 + srow) * K + chunk * 8;
    const size_t boff0 = (size_t)(bn + srow) * K + chunk * 8;
    const size_t boff1 = (size_t)(bn + 64 + srow) * K + chunk * 8;
    const unsigned loff0 = (w * 64) * 8;
    const unsigned loff1 = (256 + w * 64) * 8;

    gld_lds16(A + aoff0, sA + loff0);  gld_lds16(A + aoff1, sA + loff1);
    gld_lds16(B + boff0, sB + loff0);  gld_lds16(B + boff1, sB + loff1);

    for (int k0 = 0; k0 < K; k0 += 32) {
        __syncthreads();

        f16x8 a[4], b[4];
        #pragma unroll
        for (int i = 0; i < 4; ++i) {
            const int r = wm + i * 16 + frow;
            a[i] = *(const f16x8*)(sA + r * 32 + (fchunk ^ ((r >> 1) & 3)) * 8);
        }
        #pragma unroll
        for (int j = 0; j < 4; ++j) {
            const int r = wn + j * 16 + frow;
            b[j] = *(const f16x8*)(sB + r * 32 + (fchunk ^ ((r >> 1) & 3)) * 8);
        }

        __syncthreads();

        if (k0 + 32 < K) {
            const int kn = k0 + 32;
            gld_lds16(A + aoff0 + kn, sA + loff0);  gld_lds16(A + aoff1 + kn, sA + loff1);
            gld_lds16(B + boff0 + kn, sB + loff0);  gld_lds16(B + boff1 + kn, sB + loff1);
        }

        #pragma unroll
        for (int i = 0; i < 4; ++i)
            #pragma unroll
            for (int j = 0; j < 4; ++j)
                acc[i][j] = __builtin_amdgcn_mfma_f32_16x16x32_f16(a[i], b[j], acc[i][j], 0, 0, 0);
    }

    const int rbase = bm + wm + (lane >> 4) * 4;
    const int cbase = bn + wn + (lane & 15);
    #pragma unroll
    for (int i = 0; i < 4; ++i)
        #pragma unroll
        for (int j = 0; j < 4; ++j)
            #pragma unroll
            for (int r = 0; r < 4; ++r)
                C[(size_t)(rbase + i * 16 + r) * N + cbase + j * 16] = (OT)acc[i][j][r];
}

// ---------------------------------------------------------------------------
// 256x256-tile, 4-phase, counted-vmcnt GEMM (C = A[M,K] @ B[N,K]^T).
// Coarsened from the verified 8-phase schedule: 32 MFMA per barrier-pair
// (halves barrier/wait count — our K=1024 shape is barrier-overhead-bound at
// 8 phases). Invariants preserved: ds_read||stage||MFMA interleave per phase,
// counted vmcnt(6) (never 0 mid-loop), setprio around MFMA clusters, and
// restage-only-regions-read-a-full-barrier-pair-earlier:
//   phA reads {A0h0,B0h0,B0h1}, restages A1h1(tile 2it+1)   [read in phD(it-1)]
//   phB reads {A0h1},           restages A0h0,B0h0,B0h1(kc2)[read in phA], VM6
//   phC reads {A1h0,B1h0,B1h1}, restages A0h1(kc2)          [read in phB]
//   phD reads {A1h1},           restages A1h0,B1h0,B1h1(kc3)[read in phC], VM6
// vmcnt: before phB's VM6 in-flight = 6(phD_prev)+2(phA)+6(phB) = 14 ->
// drains 8 oldest = all of tile 2it+1 (consumed phC/phD). Before phD's VM6
// in-flight = 6+2+6 = 14 -> drains 8 = tile 2it+2 (consumed next phA/phB).
// Requires M%256==0, N%256==0, K%256==0, grid%8==0.
// ---------------------------------------------------------------------------
__device__ __forceinline__ void stage_half(const f16* __restrict__ g, size_t row0,
                                           int K, int kcol, f16* l) {
    const int t = threadIdx.x;
    #pragma unroll
    for (int i = 0; i < 2; ++i) {
        const int idx = i * 512 + t;                 // 1024 x 16B = 128 rows
        const int r = idx >> 3;
        const int qg = (idx & 7) ^ (r & 7);          // inverse (= same) swizzle
        gld_lds16(g + (row0 + r) * (size_t)K + kcol + qg * 8, l + idx * 8);
    }
}

#define BAR __builtin_amdgcn_s_barrier()
#define VM6 asm volatile("s_waitcnt vmcnt(6)" ::: "memory")
#define VM8 asm volatile("s_waitcnt vmcnt(8)" ::: "memory")
#define VM0 asm volatile("s_waitcnt vmcnt(0)" ::: "memory")

#define RD_A(S, mh)                                                         \
    { _Pragma("unroll") for (int mi = 0; mi < 4; ++mi) {                    \
        const f16* p = (S) + ((mh) * 128 + mi * 32 + arow) * 64;            \
        a[0][mi] = *(const f16x8*)(p + q0);                                 \
        a[1][mi] = *(const f16x8*)(p + q1); } }

#define RD_B(S, nh)                                                         \
    { _Pragma("unroll") for (int ni = 0; ni < 2; ++ni) {                    \
        const f16* p = (S) + (((nh) * 2 + ni) * 64 + brow) * 64;            \
        b[0][(nh) * 2 + ni] = *(const f16x8*)(p + q0);                      \
        b[1][(nh) * 2 + ni] = *(const f16x8*)(p + q1); } }

#define QUAD(mh, nh)                                                        \
    { _Pragma("unroll") for (int mi = 0; mi < 4; ++mi)                      \
      _Pragma("unroll") for (int ni = 0; ni < 2; ++ni) {                    \
          f32x4& c = acc[(mh) * 4 + mi][(nh) * 2 + ni];                     \
          c = __builtin_amdgcn_mfma_f32_16x16x32_f16(a[0][mi], b[0][(nh) * 2 + ni], c, 0, 0, 0); \
          c = __builtin_amdgcn_mfma_f32_16x16x32_f16(a[1][mi], b[1][(nh) * 2 + ni], c, 0, 0, 0); \
      } }

#define QUAD2(mh)                                                           \
    { __builtin_amdgcn_s_setprio(1); QUAD(mh, 0); QUAD(mh, 1);              \
      __builtin_amdgcn_s_setprio(0); }

template <typename OT>
__global__ __launch_bounds__(512, 2) void gemm256(const f16* __restrict__ A,
                                                  const f16* __restrict__ B,
                                                  OT* __restrict__ C,
                                                  int M, int N, int K) {
    __shared__ __align__(16) f16 smem[4 * 16384];   // 128 KiB
    f16* const sA0 = smem;
    f16* const sA1 = smem + 16384;
    f16* const sB0 = smem + 32768;
    f16* const sB1 = smem + 49152;

    const int t = threadIdx.x;
    const int lane = t & 63;
    const int w = t >> 6;
    const int wr = w >> 2;                // 0..1 (M)
    const int wc = w & 3;                 // 0..3 (N)
    const int frow = lane & 15;
    const int fc = lane >> 4;

    // XCD-aware bijective swizzle (grid size is a multiple of 8)
    const int nbx = N >> 8;
    const int nwg = gridDim.x;
    const int wg = (blockIdx.x & 7) * (nwg >> 3) + (blockIdx.x >> 3);
    const int bm = (wg / nbx) << 8;
    const int bn = (wg % nbx) << 8;

    const int arow = wr * 16 + frow;      // + m*32  (interleaved wave rows)
    const int brow = wc * 16 + frow;      // + n*64
    const int q0 = (fc ^ (frow & 7)) * 8;        // swizzled chunk, kstep 0
    const int q1 = ((4 + fc) ^ (frow & 7)) * 8;  // swizzled chunk, kstep 1

    f32x4 acc[8][4] = {};
    f16x8 a[2][4], b[2][4];

    // prologue: stage K-tiles 0 (buf0) and 1 (buf1)
    stage_half(A, bm,       K, 0,  sA0);
    stage_half(B, bn,       K, 0,  sB0);
    stage_half(B, bn + 128, K, 0,  sB0 + 8192);
    stage_half(A, bm + 128, K, 0,  sA0 + 8192);
    stage_half(A, bm,       K, 64, sA1);
    stage_half(B, bn,       K, 64, sB1);
    stage_half(B, bn + 128, K, 64, sB1 + 8192);
    stage_half(A, bm + 128, K, 64, sA1 + 8192);
    VM8;                                   // K-tile 0 landed (tile 1 in flight)
    BAR;

    const int NT = K >> 7;                 // 2 K-tiles (of 64) per iteration
    for (int it = 0; it < NT; ++it) {
        const bool lastit = (it == NT - 1);
        const int kc1 = (it * 2 + 1) << 6;
        const int kc2 = (it * 2 + 2) << 6;
        const int kc3 = (it * 2 + 3) << 6;

        // phA: consume buf0-h0 rows x all B of buf0; restage A1-h1 (tile 2it+1)
        RD_A(sA0, 0); RD_B(sB0, 0); RD_B(sB0, 1);
        if (it > 0) stage_half(A, bm + 128, K, kc1, sA1 + 8192);
        BAR; QUAD2(0); BAR;

        // phB: consume buf0-h1 rows; restage buf0 (tile 2it+2) except A-h1
        RD_A(sA0, 1);
        if (!lastit) {
            stage_half(A, bm,       K, kc2, sA0);
            stage_half(B, bn,       K, kc2, sB0);
            stage_half(B, bn + 128, K, kc2, sB0 + 8192);
            VM6;                           // tile 2it+1 fully landed
        } else {
            VM0;
        }
        BAR; QUAD2(1); BAR;

        // phC: consume buf1-h0 rows x all B of buf1; restage A0-h1 (kc2)
        RD_A(sA1, 0); RD_B(sB1, 0); RD_B(sB1, 1);
        if (!lastit) stage_half(A, bm + 128, K, kc2, sA0 + 8192);
        BAR; QUAD2(0); BAR;

        // phD: consume buf1-h1 rows; restage buf1 (tile 2it+3) except A-h1
        RD_A(sA1, 1);
        if (!lastit) {
            stage_half(A, bm,       K, kc3, sA1);
            stage_half(B, bn,       K, kc3, sB1);
            stage_half(B, bn + 128, K, kc3, sB1 + 8192);
            VM6;                           // tile 2it+2 fully landed
        }
        BAR; QUAD2(1); BAR;
    }

    // epilogue: C/D layout col = lane&15, row = (lane>>4)*4 + reg
    const size_t rb = (size_t)bm + wr * 16 + ((lane >> 4) << 2);
    const int cb = bn + wc * 16 + (lane & 15);
    #pragma unroll
    for (int m = 0; m < 8; ++m)
        #pragma unroll
        for (int n = 0; n < 4; ++n)
            #pragma unroll
            for (int rr = 0; rr < 4; ++rr)
                C[(rb + m * 32 + rr) * N + cb + n * 64] = (OT)acc[m][n][rr];
}

// ---------------------------------------------------------------------------
// Windowed attention, all-fp16 I/O, 4 rows per wave (ILP over 4 independent
// latency chains). Block = 4 waves = 4 head-groups; block b handles rows
// 4b..4b+3. lane = 16*hh + s; lane owns dims [4s, 4s+4) of head hg*4+hh.
// ---------------------------------------------------------------------------
__global__ __launch_bounds__(256) void attn_kernel(const f16* __restrict__ qh,   // (B*LQ, 1024) fp16
                                                   const f16* __restrict__ kvp,  // (B*LKV, 2048): K|V fp16
                                                   const int* __restrict__ seg_id, // (B*LQ)
                                                   f16* __restrict__ attn_o) {     // (B*LQ, 1024) fp16
    const int hg = threadIdx.x >> 6;
    const int lane = threadIdx.x & 63;
    const int r0 = blockIdx.x << 2;      // 4 consecutive rows (same batch: LQ=4096)
    const int hh = lane >> 4;
    const int s  = lane & 15;
    const int dbase = (hg * 4 + hh) * HDIM + 4 * s;
    const int b = r0 >> 12;
    const f16* kvb = kvp + (size_t)b * LKV_C * (2 * D_ATTN);

    int seg[4];
    float4 q[4];
    #pragma unroll
    for (int i = 0; i < 4; ++i) {
        seg[i] = seg_id[r0 + i];
        f16x4 qv = *(const f16x4*)(qh + (size_t)(r0 + i) * D_ATTN + dbase);
        q[i] = make_float4((float)qv.x, (float)qv.y, (float)qv.z, (float)qv.w);
    }

    // partial dots: 16 independent gathers, then 16 butterflies
    float sc[4][KW];
    #pragma unroll
    for (int i = 0; i < 4; ++i)
        #pragma unroll
        for (int w = 0; w < KW; ++w) {
            const int j = seg[i] - w;
            float p = 0.f;
            if (j >= 0) {
                f16x4 k4 = *(const f16x4*)(kvb + (size_t)j * (2 * D_ATTN) + dbase);
                p = q[i].x * (float)k4.x + q[i].y * (float)k4.y +
                    q[i].z * (float)k4.z + q[i].w * (float)k4.w;
            }
            sc[i][w] = p;
        }
    #pragma unroll
    for (int i = 0; i < 4; ++i)
        #pragma unroll
        for (int w = 0; w < KW; ++w) {
            float p = sc[i][w];
            p += __shfl_xor(p, 1);
            p += __shfl_xor(p, 2);
            p += __shfl_xor(p, 4);
            p += __shfl_xor(p, 8);
            sc[i][w] = (seg[i] - w >= 0) ? p * ATT_SCALE : -1e30f;
        }

    // softmax + V gather per row
    #pragma unroll
    for (int i = 0; i < 4; ++i) {
        const float m = fmaxf(fmaxf(sc[i][0], sc[i][1]), fmaxf(sc[i][2], sc[i][3]));
        float e[KW], sum = 0.f;
        #pragma unroll
        for (int w = 0; w < KW; ++w) {
            e[w] = __expf(sc[i][w] - m);
            sum += e[w];
        }
        const float inv = 1.f / sum;

        float4 o = make_float4(0.f, 0.f, 0.f, 0.f);
        #pragma unroll
        for (int w = 0; w < KW; ++w) {
            const int j = seg[i] - w;
            if (j >= 0) {
                f16x4 v4 = *(const f16x4*)(kvb + (size_t)j * (2 * D_ATTN) + D_ATTN + dbase);
                const float c = e[w] * inv;
                o.x = fmaf(c, (float)v4.x, o.x);
                o.y = fmaf(c, (float)v4.y, o.y);
                o.z = fmaf(c, (float)v4.z, o.z);
                o.w = fmaf(c, (float)v4.w, o.w);
            }
        }
        *(f16x4*)(attn_o + (size_t)(r0 + i) * D_ATTN + dbase) =
            (f16x4){(f16)o.x, (f16)o.y, (f16)o.z, (f16)o.w};
    }
}

extern "C" void kernel_launch(void* const* d_in, const int* in_sizes, int n_in,
                              void* d_out, int out_size, void* d_ws, size_t ws_size,
                              hipStream_t stream) {
    const float* q      = (const float*)d_in[0]; // (4,4096,1024)
    const float* kv_src = (const float*)d_in[1]; // (4,512,1024)
    const int*   seg    = (const int*)  d_in[2]; // (4,4096)
    const float* Wq     = (const float*)d_in[3]; // (1024,1024)
    const float* Wkv    = (const float*)d_in[4]; // (2048,1024)
    const float* Wo     = (const float*)d_in[5]; // (1024,1024)
    float* out = (float*)d_out;

    const int M  = B_C * LQ_C;    // 16384
    const int Mk = B_C * LKV_C;   // 2048

    // workspace layout (~52 MB)
    f16* q_hi   = (f16*)d_ws;                       // 32 MB
    f16* kvs_hi = q_hi   + (size_t)M * D_ATTN;      // 4 MB
    f16* Wq_hi  = kvs_hi + (size_t)Mk * 1024;       // 2 MB
    f16* Wkv_hi = Wq_hi  + 1024 * 1024;             // 4 MB
    f16* Wo_hi  = Wkv_hi + 2048 * 1024;             // 2 MB
    f16* kvp    = Wo_hi  + 1024 * 1024;             // 8 MB (fp16 K|V)
    f16* attn_o = q_hi;             // alias: q_hi dead after GEMM1
    f16* qh16   = (f16*)d_out;      // qh (fp16) parked in d_out, overwritten by GEMM4

    // 1. fp32 -> fp16 conversion of all inputs (single kernel)
    split_all<<<SEG_END / 256, 256, 0, stream>>>(q, kv_src, Wq, Wkv, Wo,
                                                 q_hi, kvs_hi, Wq_hi, Wkv_hi, Wo_hi);

    // 2. kvp = kv_src @ Wkv^T  (fp16)
    gemm_f16<f16><<<dim3(2048 / 128, Mk / 128), 256, 0, stream>>>(kvs_hi, Wkv_hi, kvp, Mk, 2048, 1024);
    // 3. qh16 = q @ Wq^T  (fp16, into d_out)
    gemm256<f16><<<(M / 256) * (1024 / 256), 512, 0, stream>>>(q_hi, Wq_hi, qh16, M, 1024, 1024);
    // 4. windowed attention -> fp16 attn (aliases q_hi)
    attn_kernel<<<M / 4, 256, 0, stream>>>(qh16, kvp, seg, attn_o);
    // 5. out = attn @ Wo^T  (fp32, overwrites d_out)
    gemm256<float><<<(M / 256) * (1024 / 256), 512, 0, stream>>>(attn_o, Wo_hi, out, M, 1024, 1024);
}